// Round 10
// baseline (254.191 us; speedup 1.0000x reference)
//
#include <hip/hip_runtime.h>

// ResNetVQC: 6 q3-layers of 32 three-qubit circuits + linear head.
// Each (layer,block,wire) expectation is an exact trilinear form, factorized as
//   z_w = sum_p v0[p] * ( T[w][p][.] . m[.] ),
//   m = (1, c1, s1, c2, s2, c1c2, c1s2, s1c2, s1s2),  v0 = (1, c0, s0)
// evaluated with v_dot2_f32_f16 (T quantized to f16; f32 accumulate).
//
// Round-10 structure: ZERO barriers.
//  * wave = 8 rows x 8 k-groups (lane = 8*r + kg); thread owns k in {4kg..4kg+3}
//    of ONE row -> each row's 32 blocks live inside one wave, so the "fully"
//    permutation is a within-wave LDS exchange ordered by s_waitcnt lgkmcnt(0)
//    (wave lockstep: all reads issue before all writes; LDS is in-order).
//  * consumer-order slots: S[m] = H[perm(m)]; writer stores h[i][j] at slot
//    32j+4kg+i (perm(32j+4kg+i) = 3(4kg+i)+j), reader loads slots 12kg..12kg+11
//    -> both sides are aligned float4 LDS ops; row stride 100 dwords gives even
//    8-lanes-per-bank-group on every b128 (no conflicts beyond BW minimum).
//  * T per-lane via dwordx4 (only 8 distinct addrs/instr, 16-lane dedup; 6KB
//    layer slice stays L1-resident). Layout padded to 48 hf2 per (l,k),
//    w-stride 16 hf2, so every load is 16B-aligned.
//  * angles pre-scaled by 1/2pi (folded into T + x staging): raw v_sin/v_cos,
//    no range-reduction muls. Layer-5 T unscaled (feeds classifier directly).

#define INV2PI 0.15915494309189535f

typedef _Float16 hf2 __attribute__((ext_vector_type(2)));

#if __has_builtin(__builtin_amdgcn_fdot2)
#define HAVE_FDOT2 1
#else
#define HAVE_FDOT2 0
#endif

__device__ __forceinline__ float fdot2e(hf2 a, hf2 m, float acc) {
#if HAVE_FDOT2
  return __builtin_amdgcn_fdot2(a, m, acc, false);
#else
  return fmaf((float)a.x, (float)m.x, fmaf((float)a.y, (float)m.y, acc));
#endif
}

#if __has_builtin(__builtin_amdgcn_sinf)
__device__ __forceinline__ float hwsin(float r) { return __builtin_amdgcn_sinf(r); }
__device__ __forceinline__ float hwcos(float r) { return __builtin_amdgcn_cosf(r); }
#else
__device__ __forceinline__ float hwsin(float r) { return __sinf(r * 6.2831853071795865f); }
__device__ __forceinline__ float hwcos(float r) { return __cosf(r * 6.2831853071795865f); }
#endif

// ---------------- setup kernel: build T from thetas ----------------
// grid: 6 blocks (one per q3-layer), 256 threads: k = t>>3 (32 blocks), col = t&7
__global__ __launch_bounds__(256) void build_T(const float* __restrict__ thetas,
                                               hf2* __restrict__ Thp,
                                               hf2* __restrict__ T5) {
  __shared__ float Ur[32][8][8];  // [k][col][amp]
  __shared__ float Ui[32][8][8];
  const int l = blockIdx.x;
  const int t = threadIdx.x;
  const int k = t >> 3;
  const int col = t & 7;

  float pr[8], pi[8];
#pragma unroll
  for (int j = 0; j < 8; ++j) { pr[j] = (j == col) ? 1.f : 0.f; pi[j] = 0.f; }

  const float* th = thetas + (size_t)(l * 32 + k) * 54;  // [d][w][3]
#pragma unroll
  for (int d = 0; d < 6; ++d) {
#pragma unroll
    for (int w = 0; w < 3; ++w) {
      float phi = th[(d * 3 + w) * 3 + 0];
      float tht = th[(d * 3 + w) * 3 + 1];
      float omg = th[(d * 3 + w) * 3 + 2];
      float st, ct, sp, cp, sm, cm;
      __sincosf(0.5f * tht, &st, &ct);
      __sincosf(0.5f * (phi + omg), &sp, &cp);
      __sincosf(0.5f * (phi - omg), &sm, &cm);
      float m00r =  cp * ct, m00i = -sp * ct;
      float m01r = -cm * st, m01i = -sm * st;
      float m10r =  cm * st, m10i = -sm * st;
      float m11r =  cp * ct, m11i =  sp * ct;
      const int s = 4 >> w;  // qubit0 = MSB
#pragma unroll
      for (int base = 0; base < 8; ++base) {
        if (base & s) continue;
        float ar = pr[base], ai = pi[base];
        float br = pr[base + s], bi = pi[base + s];
        pr[base]     = m00r * ar - m00i * ai + m01r * br - m01i * bi;
        pi[base]     = m00r * ai + m00i * ar + m01r * bi + m01i * br;
        pr[base + s] = m10r * ar - m10i * ai + m11r * br - m11i * bi;
        pi[base + s] = m10r * ai + m10i * ar + m11r * bi + m11i * br;
      }
    }
    const int r = (d & 1) + 1;  // CNOT ring range: 1,2,1,2,...
#pragma unroll
    for (int w = 0; w < 3; ++w) {
      const int cs = 4 >> w;
      const int ts = 4 >> ((w + r) % 3);
#pragma unroll
      for (int idx = 0; idx < 8; ++idx) {
        if (!(idx & cs) || (idx & ts)) continue;
        const int j2 = idx | ts;
        float tr = pr[idx]; pr[idx] = pr[j2]; pr[j2] = tr;
        float ti = pi[idx]; pi[idx] = pi[j2]; pi[j2] = ti;
      }
    }
  }
#pragma unroll
  for (int j = 0; j < 8; ++j) { Ur[k][col][j] = pr[j]; Ui[k][col][j] = pi[j]; }
  __syncthreads();

  if (col < 3) {
    const int w = col;  // wire
    float rem[8][8];
#pragma unroll
    for (int a = 0; a < 8; ++a) {
#pragma unroll
      for (int bb = 0; bb < 8; ++bb) {
        float acc = 0.f;
#pragma unroll
        for (int c = 0; c < 8; ++c) {
          float zs = ((c >> (2 - w)) & 1) ? -1.f : 1.f;
          acc += zs * (Ur[k][a][c] * Ur[k][bb][c] + Ui[k][a][c] * Ui[k][bb][c]);
        }
        rem[a][bb] = acc;
      }
    }
    const int   ga[3][2] = {{0, 1}, {0, 1}, {0, 1}};
    const int   gb[3][2] = {{0, 1}, {0, 1}, {1, 0}};
    const float gc[3][2] = {{0.5f, 0.5f}, {0.5f, -0.5f}, {0.5f, 0.5f}};
    // monomial index for (q,r): m = (1,c1,s1,c2,s2,c1c2,c1s2,s1c2,s1s2)
    const int MONO[3][3] = {{0, 3, 4}, {1, 5, 6}, {2, 7, 8}};
    float tv[27];
#pragma unroll
    for (int p = 0; p < 3; ++p) {
#pragma unroll
      for (int q = 0; q < 3; ++q) {
#pragma unroll
        for (int rr = 0; rr < 3; ++rr) {
          float acc = 0.f;
#pragma unroll
          for (int e0 = 0; e0 < 2; ++e0)
#pragma unroll
            for (int e1 = 0; e1 < 2; ++e1)
#pragma unroll
              for (int e2 = 0; e2 < 2; ++e2) {
                int a  = (ga[p][e0] << 2) | (ga[q][e1] << 1) | ga[rr][e2];
                int bb = (gb[p][e0] << 2) | (gb[q][e1] << 1) | gb[rr][e2];
                acc += gc[p][e0] * gc[q][e1] * gc[rr][e2] * rem[a][bb];
              }
          tv[p * 9 + MONO[q][rr]] = acc;
        }
      }
    }
    // scale layers 0-4 by 1/2pi so outputs are in revolutions (raw v_sin input)
    if (l < 5) {
#pragma unroll
      for (int i = 0; i < 27; ++i) tv[i] *= INV2PI;
      hf2* Tp = Thp + ((size_t)(l * 32 + k)) * 48 + w * 16;
#pragma unroll
      for (int p = 0; p < 3; ++p) {
#pragma unroll
        for (int d = 0; d < 4; ++d) {
          hf2 v = {(_Float16)tv[p * 9 + 2 * d], (_Float16)tv[p * 9 + 2 * d + 1]};
          Tp[p * 5 + d] = v;
        }
        hf2 v4 = {(_Float16)tv[p * 9 + 8], (_Float16)0.f};
        Tp[p * 5 + 4] = v4;
      }
      hf2 zz = {(_Float16)0.f, (_Float16)0.f};
      Tp[15] = zz;
    } else if (w == 0) {
      hf2* Tp = T5 + k * 16;
#pragma unroll
      for (int p = 0; p < 3; ++p) {
#pragma unroll
        for (int d = 0; d < 4; ++d) {
          hf2 v = {(_Float16)tv[p * 9 + 2 * d], (_Float16)tv[p * 9 + 2 * d + 1]};
          Tp[p * 5 + d] = v;
        }
        hf2 v4 = {(_Float16)tv[p * 9 + 8], (_Float16)0.f};
        Tp[p * 5 + 4] = v4;
      }
      hf2 zz = {(_Float16)0.f, (_Float16)0.f};
      Tp[15] = zz;
    }
  }
}

// ---------------- main kernel ----------------
// one 3-qubit eval, all 3 wires; tb = 48 hf2 (w-stride 16). angles in revolutions.
__device__ __forceinline__ void evalk(const hf2* __restrict__ tb,
                                      float a0, float a1, float a2,
                                      float* __restrict__ z) {
  float s0 = hwsin(a0), c0 = hwcos(a0);
  float s1 = hwsin(a1), c1 = hwcos(a1);
  float s2 = hwsin(a2), c2 = hwcos(a2);
  float m5 = c1 * c2, m6 = c1 * s2, m7 = s1 * c2, m8 = s1 * s2;
  hf2 M0 = {(_Float16)1.0f, (_Float16)c1};
  hf2 M1 = {(_Float16)s1,   (_Float16)c2};
  hf2 M2 = {(_Float16)s2,   (_Float16)m5};
  hf2 M3 = {(_Float16)m6,   (_Float16)m7};
  hf2 M4 = {(_Float16)m8,   (_Float16)0.0f};
#pragma unroll
  for (int w = 0; w < 3; ++w) {
    const hf2* tw = tb + w * 16;
    float P[3];
#pragma unroll
    for (int p = 0; p < 3; ++p) {
      const hf2* tt = tw + p * 5;
      float acc = fdot2e(tt[0], M0, 0.0f);
      acc = fdot2e(tt[1], M1, acc);
      acc = fdot2e(tt[2], M2, acc);
      acc = fdot2e(tt[3], M3, acc);
      acc = fdot2e(tt[4], M4, acc);
      P[p] = acc;
    }
    z[w] = fmaf(s0, P[2], fmaf(c0, P[1], P[0]));
  }
}

// wire-0-only eval (layer 5); tb = 16 hf2.
__device__ __forceinline__ float evalk1(const hf2* __restrict__ tb,
                                        float a0, float a1, float a2) {
  float s0 = hwsin(a0), c0 = hwcos(a0);
  float s1 = hwsin(a1), c1 = hwcos(a1);
  float s2 = hwsin(a2), c2 = hwcos(a2);
  float m5 = c1 * c2, m6 = c1 * s2, m7 = s1 * c2, m8 = s1 * s2;
  hf2 M0 = {(_Float16)1.0f, (_Float16)c1};
  hf2 M1 = {(_Float16)s1,   (_Float16)c2};
  hf2 M2 = {(_Float16)s2,   (_Float16)m5};
  hf2 M3 = {(_Float16)m6,   (_Float16)m7};
  hf2 M4 = {(_Float16)m8,   (_Float16)0.0f};
  float P[3];
#pragma unroll
  for (int p = 0; p < 3; ++p) {
    const hf2* tt = tb + p * 5;
    float acc = fdot2e(tt[0], M0, 0.0f);
    acc = fdot2e(tt[1], M1, acc);
    acc = fdot2e(tt[2], M2, acc);
    acc = fdot2e(tt[3], M3, acc);
    acc = fdot2e(tt[4], M4, acc);
    P[p] = acc;
  }
  return fmaf(s0, P[2], fmaf(c0, P[1], P[0]));
}

// 512 threads = 8 waves; wave owns 8 rows; lane = 8*rp + kg (rp=row, kg=k-group);
// thread evals k in {4kg..4kg+3}. LDS: per-wave 8 rows x 100 dwords, slot array
// S[m] = H[perm(m)]. ZERO __syncthreads in this kernel.
__global__ __launch_bounds__(512, 4) void vqc_main(const float* __restrict__ x,
                                                   const hf2* __restrict__ Thp,
                                                   const hf2* __restrict__ T5,
                                                   const float* __restrict__ wcls,
                                                   const float* __restrict__ bcls,
                                                   float* __restrict__ out) {
  __shared__ float exch[8 * 800];  // 8 waves x (8 rows x 100) = 25600 B
  const int t = threadIdx.x;
  const int wid = t >> 6;
  const int lane = t & 63;
  const int rp = lane >> 3;  // row within wave 0..7
  const int kg = lane & 7;   // k-group 0..7, k = 4kg+i

  const size_t row0 = (size_t)blockIdx.x * 64 + wid * 8;  // wave's first row
  const float* xw = x + row0 * 96;
  float* eb = exch + wid * 800;

  // stage the wave's 8 rows (768 dwords) coalesced, pre-scaled to revolutions
#pragma unroll
  for (int s = 0; s < 3; ++s) {
    int d = 4 * lane + 256 * s;
    float4 v = *(const float4*)(xw + d);
    int row = d / 96;
    int col = d - row * 96;
    float4 sv = {v.x * INV2PI, v.y * INV2PI, v.z * INV2PI, v.w * INV2PI};
    *(float4*)(eb + row * 100 + col) = sv;
  }
  asm volatile("s_waitcnt lgkmcnt(0)" ::: "memory");

  float* rowb = eb + rp * 100;
  const int rd = 12 * kg;

  float h[4][3];

  // layers 0..4: contiguous consumer-order reads, eval, residual, consumer-order writes
#pragma unroll
  for (int l = 0; l < 5; ++l) {
    float4 xv0 = *(const float4*)(rowb + rd + 0);
    float4 xv1 = *(const float4*)(rowb + rd + 4);
    float4 xv2 = *(const float4*)(rowb + rd + 8);
    const hf2* tb = Thp + ((size_t)l * 32 + 4 * kg) * 48;
    float z0[3], z1[3], z2[3], z3[3];
    evalk(tb + 0 * 48, xv0.x, xv0.y, xv0.z, z0);
    evalk(tb + 1 * 48, xv0.w, xv1.x, xv1.y, z1);
    evalk(tb + 2 * 48, xv1.z, xv1.w, xv2.x, z2);
    evalk(tb + 3 * 48, xv2.y, xv2.z, xv2.w, z3);
    if (l == 0) {
#pragma unroll
      for (int j = 0; j < 3; ++j) {
        h[0][j] = z0[j]; h[1][j] = z1[j]; h[2][j] = z2[j]; h[3][j] = z3[j];
      }
    } else {
#pragma unroll
      for (int j = 0; j < 3; ++j) {
        h[0][j] += z0[j]; h[1][j] += z1[j]; h[2][j] += z2[j]; h[3][j] += z3[j];
      }
    }
    if (l < 4) {
      // S[32j+4kg+i] = h[i][j]  (perm(32j+4kg+i) = 3(4kg+i)+j)
#pragma unroll
      for (int j = 0; j < 3; ++j) {
        float4 wv = {h[0][j], h[1][j], h[2][j], h[3][j]};
        *(float4*)(rowb + 32 * j + 4 * kg) = wv;
      }
      asm volatile("s_waitcnt lgkmcnt(0)" ::: "memory");
    }
  }

  // layer 5 (reduce, wire 0): inputs = own regs; stash z at rowb[k] (k=4kg..4kg+3)
  {
    float zs0 = evalk1(T5 + (4 * kg + 0) * 16, h[0][0], h[0][1], h[0][2]);
    float zs1 = evalk1(T5 + (4 * kg + 1) * 16, h[1][0], h[1][1], h[1][2]);
    float zs2 = evalk1(T5 + (4 * kg + 2) * 16, h[2][0], h[2][1], h[2][2]);
    float zs3 = evalk1(T5 + (4 * kg + 3) * 16, h[3][0], h[3][1], h[3][2]);
    float4 zv = {zs0, zs1, zs2, zs3};
    *(float4*)(rowb + 4 * kg) = zv;
  }
  asm volatile("s_waitcnt lgkmcnt(0)" ::: "memory");

  // classifier (within wave): 8 rows x 10 classes = 80 outputs on 64 lanes
#pragma unroll
  for (int pass = 0; pass < 2; ++pass) {
    int idx = lane + 64 * pass;
    if (idx < 80) {
      int rr = idx / 10;
      int c = idx - rr * 10;
      const float* zr = eb + rr * 100;
      float acc = bcls[c];
#pragma unroll
      for (int k2 = 0; k2 < 32; ++k2)
        acc = fmaf(zr[k2], wcls[c * 32 + k2], acc);
      out[(row0 + rr) * 10 + c] = acc;
    }
  }
}

extern "C" void kernel_launch(void* const* d_in, const int* in_sizes, int n_in,
                              void* d_out, int out_size, void* d_ws, size_t ws_size,
                              hipStream_t stream) {
  const float* x  = (const float*)d_in[0];   // (65536, 96) f32
  const float* th = (const float*)d_in[1];   // (6,32,6,3,3) f32
  const float* wc = (const float*)d_in[2];   // (10,32) f32
  const float* bc = (const float*)d_in[3];   // (10,) f32
  float* out = (float*)d_out;                // (65536,10) f32
  hf2* Thp = (hf2*)d_ws;                     // 5*32*48 = 7680 hf2 (30.7 KB), scaled
  hf2* T5  = Thp + 5 * 32 * 48;              // 32*16 = 512 hf2 (2 KB), unscaled

  build_T<<<6, 256, 0, stream>>>(th, Thp, T5);
  vqc_main<<<65536 / 64, 512, 0, stream>>>(x, Thp, T5, wc, bc, out);
}

// Round 11
// 53.983 us; speedup vs baseline: 4.7087x; 4.7087x over previous
//
#include <hip/hip_runtime.h>

// ResNetVQC: 6 q3-layers of 32 three-qubit circuits + linear head.
// Each (layer,block,wire) expectation is an exact trilinear form, factorized as
//   z_w = sum_p v0[p] * ( T[w][p][.] . m[.] ),
//   m = (1, c1, s1, c2, s2, c1c2, c1s2, s1c2, s1s2),  v0 = (1, c0, s0)
// evaluated with v_dot2_f32_f16 (T f16, f32 accumulate). T pre-scaled by 1/2pi
// (layers 0-4) so angles flow in REVOLUTIONS -> raw hw v_sin/v_cos.
//
// Round-11 structure (fixes round-10's per-lane-T disaster, keeps its wins):
//  * lane = batch row (64/block), wave ws owns k in {4ws..4ws+3}: T addresses
//    are wave-uniform -> scalar s_loads (the property round 10 broke).
//  * DOUBLE-BUFFERED f16 LDS exchange in consumer-order slots
//    (S[m] = H[perm(m)], writer (k',j') -> slot 32j'+k'): layer l reads
//    buf[l&1] (3x ds_read_b64, contiguous), writes buf[(l&1)^1] -> ONE barrier
//    per layer, 6 total (was 11). 2x64x96 f16 = 24.6KB -> 4 blocks/CU, and
//    1024 blocks tile 256 CUs exactly (no straggler tail).
//  * residual trunk h stays f32 in registers; only the permuted exchange is
//    f16-quantized (~3e-3/layer, inside the 0.068 threshold budget).

#define INV2PI 0.15915494309189535f

typedef _Float16 hf2 __attribute__((ext_vector_type(2)));
typedef _Float16 hf4 __attribute__((ext_vector_type(4)));

#if __has_builtin(__builtin_amdgcn_fdot2)
#define HAVE_FDOT2 1
#else
#define HAVE_FDOT2 0
#endif

__device__ __forceinline__ float fdot2e(hf2 a, hf2 m, float acc) {
#if HAVE_FDOT2
  return __builtin_amdgcn_fdot2(a, m, acc, false);
#else
  return fmaf((float)a.x, (float)m.x, fmaf((float)a.y, (float)m.y, acc));
#endif
}

#if __has_builtin(__builtin_amdgcn_sinf)
__device__ __forceinline__ float hwsin(float r) { return __builtin_amdgcn_sinf(r); }
__device__ __forceinline__ float hwcos(float r) { return __builtin_amdgcn_cosf(r); }
#else
__device__ __forceinline__ float hwsin(float r) { return __sinf(r * 6.2831853071795865f); }
__device__ __forceinline__ float hwcos(float r) { return __cosf(r * 6.2831853071795865f); }
#endif

// ---------------- setup kernel: build T from thetas ----------------
// grid: 6 blocks (one per q3-layer), 256 threads: k = t>>3 (32 blocks), col = t&7
__global__ __launch_bounds__(256) void build_T(const float* __restrict__ thetas,
                                               hf2* __restrict__ Thp,
                                               hf2* __restrict__ T5) {
  __shared__ float Ur[32][8][8];  // [k][col][amp]
  __shared__ float Ui[32][8][8];
  const int l = blockIdx.x;
  const int t = threadIdx.x;
  const int k = t >> 3;
  const int col = t & 7;

  float pr[8], pi[8];
#pragma unroll
  for (int j = 0; j < 8; ++j) { pr[j] = (j == col) ? 1.f : 0.f; pi[j] = 0.f; }

  const float* th = thetas + (size_t)(l * 32 + k) * 54;  // [d][w][3]
#pragma unroll
  for (int d = 0; d < 6; ++d) {
#pragma unroll
    for (int w = 0; w < 3; ++w) {
      float phi = th[(d * 3 + w) * 3 + 0];
      float tht = th[(d * 3 + w) * 3 + 1];
      float omg = th[(d * 3 + w) * 3 + 2];
      float st, ct, sp, cp, sm, cm;
      __sincosf(0.5f * tht, &st, &ct);
      __sincosf(0.5f * (phi + omg), &sp, &cp);
      __sincosf(0.5f * (phi - omg), &sm, &cm);
      float m00r =  cp * ct, m00i = -sp * ct;
      float m01r = -cm * st, m01i = -sm * st;
      float m10r =  cm * st, m10i = -sm * st;
      float m11r =  cp * ct, m11i =  sp * ct;
      const int s = 4 >> w;  // qubit0 = MSB
#pragma unroll
      for (int base = 0; base < 8; ++base) {
        if (base & s) continue;
        float ar = pr[base], ai = pi[base];
        float br = pr[base + s], bi = pi[base + s];
        pr[base]     = m00r * ar - m00i * ai + m01r * br - m01i * bi;
        pi[base]     = m00r * ai + m00i * ar + m01r * bi + m01i * br;
        pr[base + s] = m10r * ar - m10i * ai + m11r * br - m11i * bi;
        pi[base + s] = m10r * ai + m10i * ar + m11r * bi + m11i * br;
      }
    }
    const int r = (d & 1) + 1;  // CNOT ring range: 1,2,1,2,...
#pragma unroll
    for (int w = 0; w < 3; ++w) {
      const int cs = 4 >> w;
      const int ts = 4 >> ((w + r) % 3);
#pragma unroll
      for (int idx = 0; idx < 8; ++idx) {
        if (!(idx & cs) || (idx & ts)) continue;
        const int j2 = idx | ts;
        float tr = pr[idx]; pr[idx] = pr[j2]; pr[j2] = tr;
        float ti = pi[idx]; pi[idx] = pi[j2]; pi[j2] = ti;
      }
    }
  }
#pragma unroll
  for (int j = 0; j < 8; ++j) { Ur[k][col][j] = pr[j]; Ui[k][col][j] = pi[j]; }
  __syncthreads();

  if (col < 3) {
    const int w = col;  // wire
    float rem[8][8];
#pragma unroll
    for (int a = 0; a < 8; ++a) {
#pragma unroll
      for (int bb = 0; bb < 8; ++bb) {
        float acc = 0.f;
#pragma unroll
        for (int c = 0; c < 8; ++c) {
          float zs = ((c >> (2 - w)) & 1) ? -1.f : 1.f;
          acc += zs * (Ur[k][a][c] * Ur[k][bb][c] + Ui[k][a][c] * Ui[k][bb][c]);
        }
        rem[a][bb] = acc;
      }
    }
    const int   ga[3][2] = {{0, 1}, {0, 1}, {0, 1}};
    const int   gb[3][2] = {{0, 1}, {0, 1}, {1, 0}};
    const float gc[3][2] = {{0.5f, 0.5f}, {0.5f, -0.5f}, {0.5f, 0.5f}};
    // monomial index for (q,r): m = (1,c1,s1,c2,s2,c1c2,c1s2,s1c2,s1s2)
    const int MONO[3][3] = {{0, 3, 4}, {1, 5, 6}, {2, 7, 8}};
    float tv[27];
#pragma unroll
    for (int p = 0; p < 3; ++p) {
#pragma unroll
      for (int q = 0; q < 3; ++q) {
#pragma unroll
        for (int rr = 0; rr < 3; ++rr) {
          float acc = 0.f;
#pragma unroll
          for (int e0 = 0; e0 < 2; ++e0)
#pragma unroll
            for (int e1 = 0; e1 < 2; ++e1)
#pragma unroll
              for (int e2 = 0; e2 < 2; ++e2) {
                int a  = (ga[p][e0] << 2) | (ga[q][e1] << 1) | ga[rr][e2];
                int bb = (gb[p][e0] << 2) | (gb[q][e1] << 1) | gb[rr][e2];
                acc += gc[p][e0] * gc[q][e1] * gc[rr][e2] * rem[a][bb];
              }
          tv[p * 9 + MONO[q][rr]] = acc;
        }
      }
    }
    // layers 0-4: scale by 1/2pi (outputs in revolutions, feeds raw v_sin)
    if (l < 5) {
#pragma unroll
      for (int i = 0; i < 27; ++i) tv[i] *= INV2PI;
      hf2* Tp = Thp + ((size_t)(l * 32 + k)) * 48 + w * 16;
#pragma unroll
      for (int p = 0; p < 3; ++p) {
#pragma unroll
        for (int d = 0; d < 4; ++d) {
          hf2 v = {(_Float16)tv[p * 9 + 2 * d], (_Float16)tv[p * 9 + 2 * d + 1]};
          Tp[p * 5 + d] = v;
        }
        hf2 v4 = {(_Float16)tv[p * 9 + 8], (_Float16)0.f};
        Tp[p * 5 + 4] = v4;
      }
      hf2 zz = {(_Float16)0.f, (_Float16)0.f};
      Tp[15] = zz;
    } else if (w == 0) {
      // layer 5 unscaled (its output feeds the classifier directly)
      hf2* Tp = T5 + k * 16;
#pragma unroll
      for (int p = 0; p < 3; ++p) {
#pragma unroll
        for (int d = 0; d < 4; ++d) {
          hf2 v = {(_Float16)tv[p * 9 + 2 * d], (_Float16)tv[p * 9 + 2 * d + 1]};
          Tp[p * 5 + d] = v;
        }
        hf2 v4 = {(_Float16)tv[p * 9 + 8], (_Float16)0.f};
        Tp[p * 5 + 4] = v4;
      }
      hf2 zz = {(_Float16)0.f, (_Float16)0.f};
      Tp[15] = zz;
    }
  }
}

// ---------------- main kernel evals ----------------
// one 3-qubit eval, all 3 wires; tb = 48 hf2 (w-stride 16). angles in revolutions.
__device__ __forceinline__ void evalk(const hf2* __restrict__ tb,
                                      float a0, float a1, float a2,
                                      float* __restrict__ z) {
  float s0 = hwsin(a0), c0 = hwcos(a0);
  float s1 = hwsin(a1), c1 = hwcos(a1);
  float s2 = hwsin(a2), c2 = hwcos(a2);
  float m5 = c1 * c2, m6 = c1 * s2, m7 = s1 * c2, m8 = s1 * s2;
  hf2 M0 = {(_Float16)1.0f, (_Float16)c1};
  hf2 M1 = {(_Float16)s1,   (_Float16)c2};
  hf2 M2 = {(_Float16)s2,   (_Float16)m5};
  hf2 M3 = {(_Float16)m6,   (_Float16)m7};
  hf2 M4 = {(_Float16)m8,   (_Float16)0.0f};
#pragma unroll
  for (int w = 0; w < 3; ++w) {
    const hf2* tw = tb + w * 16;
    float P[3];
#pragma unroll
    for (int p = 0; p < 3; ++p) {
      const hf2* tt = tw + p * 5;
      float acc = fdot2e(tt[0], M0, 0.0f);
      acc = fdot2e(tt[1], M1, acc);
      acc = fdot2e(tt[2], M2, acc);
      acc = fdot2e(tt[3], M3, acc);
      acc = fdot2e(tt[4], M4, acc);
      P[p] = acc;
    }
    z[w] = fmaf(s0, P[2], fmaf(c0, P[1], P[0]));
  }
}

// wire-0-only eval (layer 5); tb = 16 hf2.
__device__ __forceinline__ float evalk1(const hf2* __restrict__ tb,
                                        float a0, float a1, float a2) {
  float s0 = hwsin(a0), c0 = hwcos(a0);
  float s1 = hwsin(a1), c1 = hwcos(a1);
  float s2 = hwsin(a2), c2 = hwcos(a2);
  float m5 = c1 * c2, m6 = c1 * s2, m7 = s1 * c2, m8 = s1 * s2;
  hf2 M0 = {(_Float16)1.0f, (_Float16)c1};
  hf2 M1 = {(_Float16)s1,   (_Float16)c2};
  hf2 M2 = {(_Float16)s2,   (_Float16)m5};
  hf2 M3 = {(_Float16)m6,   (_Float16)m7};
  hf2 M4 = {(_Float16)m8,   (_Float16)0.0f};
  float P[3];
#pragma unroll
  for (int p = 0; p < 3; ++p) {
    const hf2* tt = tb + p * 5;
    float acc = fdot2e(tt[0], M0, 0.0f);
    acc = fdot2e(tt[1], M1, acc);
    acc = fdot2e(tt[2], M2, acc);
    acc = fdot2e(tt[3], M3, acc);
    acc = fdot2e(tt[4], M4, acc);
    P[p] = acc;
  }
  return fmaf(s0, P[2], fmaf(c0, P[1], P[0]));
}

// 512 threads = 8 waves; lane b = batch row (64/block); wave ws owns
// k in {4ws..4ws+3}. Double-buffered f16 exchange buf[2][64][96] in
// consumer-order slots; one barrier per layer.
__global__ __launch_bounds__(512, 8) void vqc_main(const float* __restrict__ x,
                                                   const hf2* __restrict__ Thp,
                                                   const hf2* __restrict__ T5,
                                                   const float* __restrict__ wcls,
                                                   const float* __restrict__ bcls,
                                                   float* __restrict__ out) {
  __shared__ __align__(16) _Float16 buf[2][64][96];  // 24576 B
  const int t = threadIdx.x;
  const int b = t & 63;                                   // batch row in block
  const int ws = __builtin_amdgcn_readfirstlane(t >> 6);  // wave id 0..7 (scalar)
  const size_t b0 = (size_t)blockIdx.x * 64;

  // stage x coalesced, pre-scaled to revolutions, f16, natural order -> buf[0]
  const float4* xv = (const float4*)(x + b0 * 96);
#pragma unroll
  for (int i = 0; i < 3; ++i) {
    int f = t + i * 512;  // float4 index in 64x96 tile
    float4 v = xv[f];
    int d = 4 * f;
    int row = d / 96, col = d % 96;
    hf4 sv = {(_Float16)(v.x * INV2PI), (_Float16)(v.y * INV2PI),
              (_Float16)(v.z * INV2PI), (_Float16)(v.w * INV2PI)};
    *(hf4*)&buf[0][row][col] = sv;
  }
  __syncthreads();

  float h[4][3];

  // layers 0..4: read buf[l&1] (contiguous consumer-order), eval, residual,
  // write consumer-order into buf[(l&1)^1]; one barrier per layer.
#pragma unroll
  for (int l = 0; l < 5; ++l) {
    const int cur = l & 1;
    float xin[12];
#pragma unroll
    for (int u = 0; u < 3; ++u) {
      hf4 v = *(const hf4*)&buf[cur][b][12 * ws + 4 * u];
      xin[4 * u + 0] = (float)v.x; xin[4 * u + 1] = (float)v.y;
      xin[4 * u + 2] = (float)v.z; xin[4 * u + 3] = (float)v.w;
    }
    const hf2* tb = Thp + ((size_t)l * 32 + 4 * ws) * 48;
    float z0[3], z1[3], z2[3], z3[3];
    evalk(tb + 0 * 48, xin[0], xin[1],  xin[2],  z0);
    evalk(tb + 1 * 48, xin[3], xin[4],  xin[5],  z1);
    evalk(tb + 2 * 48, xin[6], xin[7],  xin[8],  z2);
    evalk(tb + 3 * 48, xin[9], xin[10], xin[11], z3);
    if (l == 0) {
#pragma unroll
      for (int j = 0; j < 3; ++j) {
        h[0][j] = z0[j]; h[1][j] = z1[j]; h[2][j] = z2[j]; h[3][j] = z3[j];
      }
    } else {
#pragma unroll
      for (int j = 0; j < 3; ++j) {
        h[0][j] += z0[j]; h[1][j] += z1[j]; h[2][j] += z2[j]; h[3][j] += z3[j];
      }
    }
    if (l < 4) {
      // S[32j+4ws+i] = h[i][j]  (perm(32j+4ws+i) = 3(4ws+i)+j)
#pragma unroll
      for (int j = 0; j < 3; ++j) {
        hf4 wv = {(_Float16)h[0][j], (_Float16)h[1][j],
                  (_Float16)h[2][j], (_Float16)h[3][j]};
        *(hf4*)&buf[cur ^ 1][b][32 * j + 4 * ws] = wv;
      }
      __syncthreads();
    }
  }

  // layer 5 (reduce, wire 0): inputs = own regs (natural order); buf[1] is free
  {
    float zs0 = evalk1(T5 + (4 * ws + 0) * 16, h[0][0], h[0][1], h[0][2]);
    float zs1 = evalk1(T5 + (4 * ws + 1) * 16, h[1][0], h[1][1], h[1][2]);
    float zs2 = evalk1(T5 + (4 * ws + 2) * 16, h[2][0], h[2][1], h[2][2]);
    float zs3 = evalk1(T5 + (4 * ws + 3) * 16, h[3][0], h[3][1], h[3][2]);
    hf4 zv = {(_Float16)zs0, (_Float16)zs1, (_Float16)zs2, (_Float16)zs3};
    *(hf4*)&buf[1][b][4 * ws] = zv;
  }
  __syncthreads();

  // classifier: out[b][c] = sum_k z[b][k] * wcls[c][k] + bcls[c]
  for (int idx = t; idx < 640; idx += 512) {
    int bb = idx / 10, c = idx % 10;
    float acc = bcls[c];
#pragma unroll
    for (int k = 0; k < 32; ++k)
      acc = fmaf((float)buf[1][bb][k], wcls[c * 32 + k], acc);
    out[(b0 + bb) * 10 + c] = acc;
  }
}

extern "C" void kernel_launch(void* const* d_in, const int* in_sizes, int n_in,
                              void* d_out, int out_size, void* d_ws, size_t ws_size,
                              hipStream_t stream) {
  const float* x  = (const float*)d_in[0];   // (65536, 96) f32
  const float* th = (const float*)d_in[1];   // (6,32,6,3,3) f32
  const float* wc = (const float*)d_in[2];   // (10,32) f32
  const float* bc = (const float*)d_in[3];   // (10,) f32
  float* out = (float*)d_out;                // (65536,10) f32
  hf2* Thp = (hf2*)d_ws;                     // 5*32*48 = 7680 hf2 (30.7 KB), scaled
  hf2* T5  = Thp + 5 * 32 * 48;              // 32*16 = 512 hf2 (2 KB), unscaled

  build_T<<<6, 256, 0, stream>>>(th, Thp, T5);
  vqc_main<<<65536 / 64, 512, 0, stream>>>(x, Thp, T5, wc, bc, out);
}